// Round 7
// baseline (347.680 us; speedup 1.0000x reference)
//
#include <hip/hip_runtime.h>
#include <hip/hip_bf16.h>

// Problem constants (fixed by setup_inputs)
#define B_    2
#define LQ    21760
#define NROW  (B_*LQ)      // 43520 = 340*128
#define CDIM  256
#define DFF   1024

typedef __attribute__((ext_vector_type(8))) short bf16x8;
typedef __attribute__((ext_vector_type(4))) float f32x4;

static __device__ __forceinline__ ushort f2bf(float f) {
    union { float f; unsigned u; } v; v.f = f;
    unsigned u = v.u;
    return (ushort)((u + 0x7fffu + ((u >> 16) & 1u)) >> 16);
}
static __device__ __forceinline__ float u2f(unsigned u) {
    union { unsigned u; float f; } v; v.u = u; return v.f;
}
static __device__ __forceinline__ float bf2f(ushort h) {
    return u2f(((unsigned)h) << 16);
}
// chunk swizzle: permute 16B chunks within each 64-short K-block by row&7.
// Producers store with this; GEMM ds_read undoes it via byte^((lr&7)<<4).
static __device__ __forceinline__ int swzc(int row, int col) {
    return (col & ~63) | (col & 7) | ((((col >> 3) ^ row) & 7) << 3);
}
// global -> LDS direct (16B per lane)
static __device__ __forceinline__ void gload16(const void* g, void* l) {
    __builtin_amdgcn_global_load_lds(
        (const __attribute__((address_space(1))) unsigned*)g,
        (__attribute__((address_space(3))) unsigned*)l, 16, 0, 0);
}

// ---------------------------------------------------------------- elementwise
// q = src + pos; emit SWIZZLED bf16 copies of src and q (GEMM-A inputs)
__global__ void addpos_cast(const float* __restrict__ src, const float* __restrict__ pos,
                            ushort* __restrict__ s16, ushort* __restrict__ q16) {
    int i = blockIdx.x * blockDim.x + threadIdx.x;
    int stride = gridDim.x * blockDim.x;
    const float4* s4 = (const float4*)src;
    const float4* p4 = (const float4*)pos;
    const int n4 = NROW * 64;
    for (; i < n4; i += stride) {
        float4 s = s4[i], p = p4[i];
        ushort4 a, b;
        a.x = f2bf(s.x); a.y = f2bf(s.y); a.z = f2bf(s.z); a.w = f2bf(s.w);
        b.x = f2bf(s.x + p.x); b.y = f2bf(s.y + p.y);
        b.z = f2bf(s.z + p.z); b.w = f2bf(s.w + p.w);
        int row = i >> 6, col = (i & 63) * 4;
        int idx = row * 256 + swzc(row, col);
        *(ushort4*)(s16 + idx) = a;
        *(ushort4*)(q16 + idx) = b;
    }
}

// All weight transposes (swizzled) + concat bias in one launch.
static __device__ __forceinline__ void wt_one(const float* W, ushort* Wt, int K, int N, int i) {
    int n = i / K, k = i - n * K;
    Wt[(size_t)n * K + swzc(n, k)] = f2bf(W[(size_t)k * N + n]);
}
__global__ void wtrans_all(const float* Wv, const float* Woff, const float* Wa,
                           const float* Wo, const float* W1, const float* W2,
                           const float* boff, const float* ba,
                           ushort* WvT, ushort* WqT, ushort* WoT,
                           ushort* W1T, ushort* W2T, float* bq) {
    int gid = blockIdx.x * 256 + threadIdx.x;   // 2946*256 = 754176 >= 754048
    if (gid < 65536)  { wt_one(Wv, WvT, 256, 256, gid); return; }
    if (gid < 163840) {                // WqT[384][256]: Woff cols 0..255, Wa cols 256..383
        int i = gid - 65536;
        int n = i >> 8, k = i & 255;
        float v = (n < 256) ? Woff[(size_t)k * 256 + n] : Wa[(size_t)k * 128 + (n - 256)];
        WqT[n * 256 + swzc(n, k)] = f2bf(v);
        return;
    }
    if (gid < 229376) { wt_one(Wo, WoT, 256, 256,  gid - 163840); return; }
    if (gid < 491520) { wt_one(W1, W1T, 256, 1024, gid - 229376); return; }
    if (gid < 753664) { wt_one(W2, W2T, 1024, 256, gid - 491520); return; }
    if (gid < 754048) {
        int i = gid - 753664;
        bq[i] = (i < 256) ? boff[i] : ba[i - 256];
    }
}

// ---------------------------------------------------------------- GEMM (m97 structure)
// C[M][N] = A[M][K]*B[K][N] (+bias, opt relu). A,Bt chunk-swizzled bf16; Bt=B^T [N][K].
// 128x128 tile, BK=64, 4 waves (2x2), per-wave 64x64 via 4x4 16x16x32 MFMA frags.
template<int RELU, int OUTBF16, int SWZOUT>
__global__ __launch_bounds__(256) void gemm_bf16(
    const ushort* __restrict__ A, const ushort* __restrict__ Bt,
    const float* __restrict__ bias,
    float* __restrict__ Cf, ushort* __restrict__ Ch, int K, int N) {
    __shared__ __align__(16) ushort As[128 * 64];
    __shared__ __align__(16) ushort Bs[128 * 64];
    const int tid  = threadIdx.x;
    const int bm   = blockIdx.x * 128;
    const int bn   = blockIdx.y * 128;
    const int w    = tid >> 6, lane = tid & 63;
    const int wm   = (w >> 1) * 64, wn = (w & 1) * 64;
    const int lr   = lane & 15, lk = lane >> 4;
    const int srow = tid >> 3;            // 0..31
    const int sch  = tid & 7;             // 16B chunk

    f32x4 acc[4][4] = {};

    const ushort* Ab = A  + (size_t)(bm + srow) * K + sch * 8;
    const ushort* Bb = Bt + (size_t)(bn + srow) * K + sch * 8;
    ushort* Asd = &As[srow * 64 + sch * 8];
    ushort* Bsd = &Bs[srow * 64 + sch * 8];

    for (int k0 = 0; k0 < K; k0 += 64) {
        #pragma unroll
        for (int c = 0; c < 4; c++)
            gload16(Ab + (size_t)c * 32 * K + k0, Asd + c * 2048);
        #pragma unroll
        for (int c = 0; c < 4; c++)
            gload16(Bb + (size_t)c * 32 * K + k0, Bsd + c * 2048);
        __syncthreads();
        #pragma unroll
        for (int ks = 0; ks < 2; ks++) {
            bf16x8 af[4], bfr[4];
            #pragma unroll
            for (int m = 0; m < 4; m++) {
                int row = wm + m * 16 + lr;
                int byte = (row * 128 + ks * 64 + lk * 16) ^ ((lr & 7) << 4);
                af[m] = *(const bf16x8*)((const char*)As + byte);
            }
            #pragma unroll
            for (int n = 0; n < 4; n++) {
                int row = wn + n * 16 + lr;
                int byte = (row * 128 + ks * 64 + lk * 16) ^ ((lr & 7) << 4);
                bfr[n] = *(const bf16x8*)((const char*)Bs + byte);
            }
            #pragma unroll
            for (int m = 0; m < 4; m++)
                #pragma unroll
                for (int n = 0; n < 4; n++)
                    acc[m][n] = __builtin_amdgcn_mfma_f32_16x16x32_bf16(af[m], bfr[n], acc[m][n], 0, 0, 0);
        }
        __syncthreads();
    }
    // Epilogue. D: col = lane&15, row = (lane>>4)*4 + i
    #pragma unroll
    for (int m = 0; m < 4; m++) {
        int row = bm + wm + m * 16 + lk * 4;
        #pragma unroll
        for (int n = 0; n < 4; n++) {
            int col = bn + wn + n * 16 + lr;
            float bb = bias ? bias[col] : 0.f;
            #pragma unroll
            for (int i = 0; i < 4; i++) {
                float v = acc[m][n][i] + bb;
                if (RELU) v = v > 0.f ? v : 0.f;
                if (OUTBF16) {
                    int cc = SWZOUT ? swzc(row + i, col) : col;
                    Ch[(size_t)(row + i) * N + cc] = f2bf(v);
                } else {
                    Cf[(size_t)(row + i) * N + col] = v;
                }
            }
        }
    }
}

// ---------------------------------------------------------------- GEMM + residual + LayerNorm
// N fixed at 256 (one row per block tile width). 128x256 tile, 4 waves 2x2,
// per-wave 64x128 (4 M-frags x 8 N-frags). Epilogue: vv = acc+bias+resid,
// per-half row stats via 16-lane shfl, cross-half combine via LDS, LN, store.
// MODE 0: resid = f32 (src), out = bf16 swizzled (x16)
// MODE 1: resid = bf16 swizzled (x16), out = f32 (d_out)
template<int MODE>
__global__ __launch_bounds__(256) void gemm_ln(
    const ushort* __restrict__ A, const ushort* __restrict__ Bt,
    const float* __restrict__ bias,
    const float* __restrict__ residf, const ushort* __restrict__ residh,
    const float* __restrict__ g, const float* __restrict__ be,
    float* __restrict__ outf, ushort* __restrict__ outh, int K) {
    __shared__ __align__(16) ushort As[128 * 64];
    __shared__ __align__(16) ushort Bs[256 * 64];
    __shared__ float red[2][128][2];
    const int tid  = threadIdx.x;
    const int bm   = blockIdx.x * 128;
    const int w    = tid >> 6, lane = tid & 63;
    const int wm   = (w >> 1) * 64, wn = (w & 1) * 128;
    const int wni  = (w & 1);
    const int lr   = lane & 15, lk = lane >> 4;
    const int srow = tid >> 3, sch = tid & 7;

    f32x4 acc[4][8] = {};

    const ushort* Ab = A  + (size_t)(bm + srow) * K + sch * 8;
    const ushort* Bb = Bt + (size_t)srow * K + sch * 8;
    ushort* Asd = &As[srow * 64 + sch * 8];
    ushort* Bsd = &Bs[srow * 64 + sch * 8];

    for (int k0 = 0; k0 < K; k0 += 64) {
        #pragma unroll
        for (int c = 0; c < 4; c++)
            gload16(Ab + (size_t)c * 32 * K + k0, Asd + c * 2048);
        #pragma unroll
        for (int c = 0; c < 8; c++)
            gload16(Bb + (size_t)c * 32 * K + k0, Bsd + c * 2048);
        __syncthreads();
        #pragma unroll
        for (int ks = 0; ks < 2; ks++) {
            bf16x8 af[4], bfr[8];
            #pragma unroll
            for (int m = 0; m < 4; m++) {
                int row = wm + m * 16 + lr;
                int byte = (row * 128 + ks * 64 + lk * 16) ^ ((lr & 7) << 4);
                af[m] = *(const bf16x8*)((const char*)As + byte);
            }
            #pragma unroll
            for (int n = 0; n < 8; n++) {
                int row = wn + n * 16 + lr;
                int byte = (row * 128 + ks * 64 + lk * 16) ^ ((lr & 7) << 4);
                bfr[n] = *(const bf16x8*)((const char*)Bs + byte);
            }
            #pragma unroll
            for (int m = 0; m < 4; m++)
                #pragma unroll
                for (int n = 0; n < 8; n++)
                    acc[m][n] = __builtin_amdgcn_mfma_f32_16x16x32_bf16(af[m], bfr[n], acc[m][n], 0, 0, 0);
        }
        __syncthreads();
    }

    // per-lane column params (cols wn + n*16 + lr)
    float bias_r[8], g_r[8], be_r[8];
    #pragma unroll
    for (int n = 0; n < 8; n++) {
        int col = wn + n * 16 + lr;
        bias_r[n] = bias[col]; g_r[n] = g[col]; be_r[n] = be[col];
    }
    // pass 1: vv = acc + bias + resid (in place), half-row partial stats -> LDS
    #pragma unroll
    for (int m = 0; m < 4; m++) {
        #pragma unroll
        for (int i = 0; i < 4; i++) {
            int lrow = wm + m * 16 + lk * 4 + i;
            int row  = bm + lrow;
            float s = 0.f, s2 = 0.f;
            #pragma unroll
            for (int n = 0; n < 8; n++) {
                int col = wn + n * 16 + lr;
                float r;
                if (MODE == 0) r = residf[(size_t)row * 256 + col];
                else           r = bf2f(residh[(size_t)row * 256 + swzc(row, col)]);
                float v = acc[m][n][i] + bias_r[n] + r;
                acc[m][n][i] = v;
                s += v; s2 += v * v;
            }
            #pragma unroll
            for (int msk = 1; msk < 16; msk <<= 1) {
                s += __shfl_xor(s, msk); s2 += __shfl_xor(s2, msk);
            }
            if (lr == 0) { red[wni][lrow][0] = s; red[wni][lrow][1] = s2; }
        }
    }
    __syncthreads();
    // pass 2: combine halves, normalize, store
    #pragma unroll
    for (int m = 0; m < 4; m++) {
        #pragma unroll
        for (int i = 0; i < 4; i++) {
            int lrow = wm + m * 16 + lk * 4 + i;
            int row  = bm + lrow;
            float s  = red[0][lrow][0] + red[1][lrow][0];
            float s2 = red[0][lrow][1] + red[1][lrow][1];
            float mu  = s * (1.f / 256.f);
            float var = s2 * (1.f / 256.f) - mu * mu;
            float rs  = rsqrtf(var + 1e-5f);
            #pragma unroll
            for (int n = 0; n < 8; n++) {
                int col = wn + n * 16 + lr;
                float o = (acc[m][n][i] - mu) * rs * g_r[n] + be_r[n];
                if (MODE == 0) outh[(size_t)row * 256 + swzc(row, col)] = f2bf(o);
                else           outf[(size_t)row * 256 + col] = o;
            }
        }
    }
}

// ---------------------------------------------------------------- deform attn
// 1 wave per (b,query) row; 4 rows per block.
// Phase A: lane = h*8+j computes points {2j,2j+1} of head h -> SoA LDS records
// Phase B: lane = h*8+c4 gathers 64 corners for channels [c4*4, c4*4+4)
__global__ __launch_bounds__(256) void deform_attn(
    const ushort* __restrict__ val16,  // [B][LQ][256] bf16 linear
    const ushort* __restrict__ qout,   // [NROW][384] bf16: [0,256)=offs, [256,384)=logits
    const float* __restrict__ rp,      // [NROW][4][2]
    ushort* __restrict__ out16) {      // [NROW][256] bf16 SWIZZLED
    __shared__ __align__(16) unsigned offs_s[4][8][68];
    __shared__ __align__(16) float    wgts_s[4][8][68];
    const int wid  = threadIdx.x >> 6;
    const int row  = blockIdx.x * 4 + wid;
    const int lane = threadIdx.x & 63;
    const int h    = lane >> 3;
    const int j    = lane & 7;
    const int b    = row / LQ;

    const ushort* qrow = qout + (size_t)row * 384;

    // ---- phase A: softmax (8-lane group reduce) + 2 points per lane
    unsigned lgu = *(const unsigned*)(qrow + 256 + h * 16 + j * 2);
    float lgx = u2f(lgu << 16), lgy = u2f(lgu & 0xffff0000u);
    float m = fmaxf(lgx, lgy);
    m = fmaxf(m, __shfl_xor(m, 1, 8));
    m = fmaxf(m, __shfl_xor(m, 2, 8));
    m = fmaxf(m, __shfl_xor(m, 4, 8));
    float e0 = __expf(lgx - m), e1 = __expf(lgy - m);
    float s = e0 + e1;
    s += __shfl_xor(s, 1, 8);
    s += __shfl_xor(s, 2, 8);
    s += __shfl_xor(s, 4, 8);
    const float inv = 1.f / s;

    const int L  = j >> 1;              // both points of this lane share a level
    const int Wl = 128 >> L;
    const int s0 = (L == 0) ? 0 : (L == 1) ? 16384 : (L == 2) ? 20480 : 21504;
    const float fW = (float)Wl;
    float2 rr = *(const float2*)(rp + (size_t)row * 8 + L * 2);
    uint2 ou  = *(const uint2*)(qrow + h * 32 + j * 4);
    float oxv[2] = { u2f(ou.x << 16), u2f(ou.y << 16) };
    float oyv[2] = { u2f(ou.x & 0xffff0000u), u2f(ou.y & 0xffff0000u) };
    float ev[2]  = { e0, e1 };

    #pragma unroll
    for (int pt = 0; pt < 2; pt++) {
        float aw = ev[pt] * inv;
        float x = rr.x * fW + oxv[pt] - 0.5f;
        float y = rr.y * fW + oyv[pt] - 0.5f;
        float xf = floorf(x), yf = floorf(y);
        float lx = x - xf, ly = y - yf;
        int x0 = (int)xf, y0 = (int)yf;
        int x1 = x0 + 1, y1 = y0 + 1;
        int x0c = min(max(x0, 0), Wl - 1), x1c = min(max(x1, 0), Wl - 1);
        int y0c = min(max(y0, 0), Wl - 1), y1c = min(max(y1, 0), Wl - 1);
        bool vx0 = (unsigned)x0 < (unsigned)Wl, vx1 = (unsigned)x1 < (unsigned)Wl;
        bool vy0 = (unsigned)y0 < (unsigned)Wl, vy1 = (unsigned)y1 < (unsigned)Wl;
        float wx1 = lx, wx0 = 1.f - lx, wy1 = ly, wy0 = 1.f - ly;
        float w00 = (vy0 & vx0) ? aw * wy0 * wx0 : 0.f;
        float w01 = (vy0 & vx1) ? aw * wy0 * wx1 : 0.f;
        float w10 = (vy1 & vx0) ? aw * wy1 * wx0 : 0.f;
        float w11 = (vy1 & vx1) ? aw * wy1 * wx1 : 0.f;
        unsigned hb = (unsigned)h * 64u;
        unsigned o00 = (unsigned)(s0 + y0c * Wl + x0c) * 512u + hb;
        unsigned o01 = (unsigned)(s0 + y0c * Wl + x1c) * 512u + hb;
        unsigned o10 = (unsigned)(s0 + y1c * Wl + x0c) * 512u + hb;
        unsigned o11 = (unsigned)(s0 + y1c * Wl + x1c) * 512u + hb;
        *(uint4*)&offs_s[wid][h][j * 8 + pt * 4] = make_uint4(o00, o01, o10, o11);
        *(float4*)&wgts_s[wid][h][j * 8 + pt * 4] =
            make_float4(w00, w01, w10, w11);
    }
    __syncthreads();

    // ---- phase B: gather. c4 = j
    const int bu = __builtin_amdgcn_readfirstlane(b);  // wave-uniform -> SGPR base
    const char* ubase = (const char*)val16 + (size_t)bu * (LQ * 512);
    const unsigned coff = (unsigned)j * 8u;
    const unsigned* po = &offs_s[wid][h][0];
    const float*    pw = &wgts_s[wid][h][0];
    float a0 = 0.f, a1 = 0.f, a2 = 0.f, a3 = 0.f;
    #pragma unroll 8
    for (int i4 = 0; i4 < 16; i4++) {
        uint4  oo = *(const uint4*)(po + i4 * 4);
        float4 ww = *(const float4*)(pw + i4 * 4);
        uint2 u0 = *(const uint2*)(ubase + (oo.x + coff));
        uint2 u1 = *(const uint2*)(ubase + (oo.y + coff));
        uint2 u2v = *(const uint2*)(ubase + (oo.z + coff));
        uint2 u3 = *(const uint2*)(ubase + (oo.w + coff));
        a0 += ww.x * u2f(u0.x << 16); a1 += ww.x * u2f(u0.x);
        a2 += ww.x * u2f(u0.y << 16); a3 += ww.x * u2f(u0.y);
        a0 += ww.y * u2f(u1.x << 16); a1 += ww.y * u2f(u1.x);
        a2 += ww.y * u2f(u1.y << 16); a3 += ww.y * u2f(u1.y);
        a0 += ww.z * u2f(u2v.x << 16); a1 += ww.z * u2f(u2v.x);
        a2 += ww.z * u2f(u2v.y << 16); a3 += ww.z * u2f(u2v.y);
        a0 += ww.w * u2f(u3.x << 16); a1 += ww.w * u2f(u3.x);
        a2 += ww.w * u2f(u3.y << 16); a3 += ww.w * u2f(u3.y);
    }
    ushort4 o4;
    o4.x = f2bf(a0); o4.y = f2bf(a1);
    o4.z = f2bf(a2); o4.w = f2bf(a3);
    int col = h * 32 + j * 4;
    *(ushort4*)(out16 + (size_t)row * 256 + swzc(row, col)) = o4;
}

// ---------------------------------------------------------------- launch
extern "C" void kernel_launch(void* const* d_in, const int* in_sizes, int n_in,
                              void* d_out, int out_size, void* d_ws, size_t ws_size,
                              hipStream_t stream) {
    const float* src  = (const float*)d_in[0];
    const float* pos  = (const float*)d_in[1];
    const float* rp   = (const float*)d_in[2];
    const float* Wv   = (const float*)d_in[5];  const float* bv   = (const float*)d_in[6];
    const float* Woff = (const float*)d_in[7];  const float* boff = (const float*)d_in[8];
    const float* Wa   = (const float*)d_in[9];  const float* ba   = (const float*)d_in[10];
    const float* Wo   = (const float*)d_in[11]; const float* bo   = (const float*)d_in[12];
    const float* W1   = (const float*)d_in[13]; const float* b1   = (const float*)d_in[14];
    const float* W2   = (const float*)d_in[15]; const float* b2   = (const float*)d_in[16];
    const float* g1   = (const float*)d_in[17]; const float* be1  = (const float*)d_in[18];
    const float* g2w  = (const float*)d_in[19]; const float* be2  = (const float*)d_in[20];

    char* ws = (char*)d_ws;
    ushort* s16    = (ushort*)(ws + 0);            // 22,282,240 (swz)
    ushort* q16    = (ushort*)(ws + 22282240);     // 22,282,240 (swz)
    ushort* val16  = (ushort*)(ws + 44564480);     // 22,282,240 (linear)
    ushort* qout16 = (ushort*)(ws + 66846720);     // 33,423,360 (linear, [NROW][384])
    ushort* def16  = (ushort*)(ws + 100270080);    // 22,282,240 (swz)
    ushort* x16    = (ushort*)(ws + 144834560);    // 22,282,240 (swz)
    ushort* wts    = (ushort*)(ws + 167116800);    // ~1.5 MB
    ushort* hid16  = (ushort*)(ws + 44564480);     // reuse val16+qout16+def16 (89,128,960; swz)

    ushort* WvT = wts;
    ushort* WqT = WvT + 65536;      // [384][256] (Woff|Wa)
    ushort* WoT = WqT + 98304;
    ushort* W1T = WoT + 65536;
    ushort* W2T = W1T + 262144;
    float*  bq  = (float*)(W2T + 262144);  // [384] = boff|ba

    wtrans_all<<<2946, 256, 0, stream>>>(Wv, Woff, Wa, Wo, W1, W2, boff, ba,
                                         WvT, WqT, WoT, W1T, W2T, bq);

    addpos_cast<<<2048, 256, 0, stream>>>(src, pos, s16, q16);

    dim3 gv2(NROW / 128, 2), gq3(NROW / 128, 3), gf8(NROW / 128, 8);
    gemm_bf16<0,1,0><<<gv2, 256, 0, stream>>>(s16, WvT, bv, nullptr, val16,  256, 256);
    gemm_bf16<0,1,0><<<gq3, 256, 0, stream>>>(q16, WqT, bq, nullptr, qout16, 256, 384);

    deform_attn<<<NROW / 4, 256, 0, stream>>>(val16, qout16, rp, def16);

    // Wo GEMM + residual(src) + LN1 -> x16 (swz bf16)
    gemm_ln<0><<<dim3(NROW / 128), 256, 0, stream>>>(
        def16, WoT, bo, src, nullptr, g1, be1, nullptr, x16, 256);

    gemm_bf16<1,1,1><<<gf8, 256, 0, stream>>>(x16, W1T, b1, nullptr, hid16, 256, 1024);

    // W2 GEMM + residual(x16) + LN2 -> d_out (f32)
    gemm_ln<1><<<dim3(NROW / 128), 256, 0, stream>>>(
        hid16, W2T, b2, nullptr, x16, g2w, be2, (float*)d_out, nullptr, 1024);
}

// Round 8
// 306.447 us; speedup vs baseline: 1.1346x; 1.1346x over previous
//
#include <hip/hip_runtime.h>
#include <hip/hip_bf16.h>

// Problem constants (fixed by setup_inputs)
#define B_    2
#define LQ    21760
#define NROW  (B_*LQ)      // 43520 = 340*128
#define CDIM  256
#define DFF   1024

typedef __attribute__((ext_vector_type(8))) short bf16x8;
typedef __attribute__((ext_vector_type(4))) float f32x4;

static __device__ __forceinline__ ushort f2bf(float f) {
    union { float f; unsigned u; } v; v.f = f;
    unsigned u = v.u;
    return (ushort)((u + 0x7fffu + ((u >> 16) & 1u)) >> 16);
}
static __device__ __forceinline__ float u2f(unsigned u) {
    union { unsigned u; float f; } v; v.u = u; return v.f;
}
static __device__ __forceinline__ float bf2f(ushort h) {
    return u2f(((unsigned)h) << 16);
}
// chunk swizzle: permute 16B chunks within each 64-short K-block by row&7.
// Producers store with this; GEMM ds_read undoes it via byte^((lr&7)<<4).
static __device__ __forceinline__ int swzc(int row, int col) {
    return (col & ~63) | (col & 7) | ((((col >> 3) ^ row) & 7) << 3);
}
// global -> LDS direct (16B per lane)
static __device__ __forceinline__ void gload16(const void* g, void* l) {
    __builtin_amdgcn_global_load_lds(
        (const __attribute__((address_space(1))) unsigned*)g,
        (__attribute__((address_space(3))) unsigned*)l, 16, 0, 0);
}

// ---------------------------------------------------------------- elementwise
// q = src + pos; emit SWIZZLED bf16 copies of src and q (GEMM-A inputs)
__global__ void addpos_cast(const float* __restrict__ src, const float* __restrict__ pos,
                            ushort* __restrict__ s16, ushort* __restrict__ q16) {
    int i = blockIdx.x * blockDim.x + threadIdx.x;
    int stride = gridDim.x * blockDim.x;
    const float4* s4 = (const float4*)src;
    const float4* p4 = (const float4*)pos;
    const int n4 = NROW * 64;
    for (; i < n4; i += stride) {
        float4 s = s4[i], p = p4[i];
        ushort4 a, b;
        a.x = f2bf(s.x); a.y = f2bf(s.y); a.z = f2bf(s.z); a.w = f2bf(s.w);
        b.x = f2bf(s.x + p.x); b.y = f2bf(s.y + p.y);
        b.z = f2bf(s.z + p.z); b.w = f2bf(s.w + p.w);
        int row = i >> 6, col = (i & 63) * 4;
        int idx = row * 256 + swzc(row, col);
        *(ushort4*)(s16 + idx) = a;
        *(ushort4*)(q16 + idx) = b;
    }
}

// All weight transposes (swizzled) + concat bias in one launch.
static __device__ __forceinline__ void wt_one(const float* W, ushort* Wt, int K, int N, int i) {
    int n = i / K, k = i - n * K;
    Wt[(size_t)n * K + swzc(n, k)] = f2bf(W[(size_t)k * N + n]);
}
__global__ void wtrans_all(const float* Wv, const float* Woff, const float* Wa,
                           const float* Wo, const float* W1, const float* W2,
                           const float* boff, const float* ba,
                           ushort* WvT, ushort* WqT, ushort* WoT,
                           ushort* W1T, ushort* W2T, float* bq) {
    int gid = blockIdx.x * 256 + threadIdx.x;   // 2946*256 = 754176 >= 754048
    if (gid < 65536)  { wt_one(Wv, WvT, 256, 256, gid); return; }
    if (gid < 163840) {                // WqT[384][256]: Woff cols 0..255, Wa cols 256..383
        int i = gid - 65536;
        int n = i >> 8, k = i & 255;
        float v = (n < 256) ? Woff[(size_t)k * 256 + n] : Wa[(size_t)k * 128 + (n - 256)];
        WqT[n * 256 + swzc(n, k)] = f2bf(v);
        return;
    }
    if (gid < 229376) { wt_one(Wo, WoT, 256, 256,  gid - 163840); return; }
    if (gid < 491520) { wt_one(W1, W1T, 256, 1024, gid - 229376); return; }
    if (gid < 753664) { wt_one(W2, W2T, 1024, 256, gid - 491520); return; }
    if (gid < 754048) {
        int i = gid - 753664;
        bq[i] = (i < 256) ? boff[i] : ba[i - 256];
    }
}

// ---------------------------------------------------------------- GEMM (m97 structure)
// C[M][N] = A[M][K]*B[K][N] (+bias, opt relu). A,Bt chunk-swizzled bf16; Bt=B^T [N][K].
// 128x128 tile, BK=64, 4 waves (2x2), per-wave 64x64 via 4x4 16x16x32 MFMA frags.
template<int RELU, int OUTBF16, int SWZOUT>
__global__ __launch_bounds__(256) void gemm_bf16(
    const ushort* __restrict__ A, const ushort* __restrict__ Bt,
    const float* __restrict__ bias,
    float* __restrict__ Cf, ushort* __restrict__ Ch, int K, int N) {
    __shared__ __align__(16) ushort As[128 * 64];
    __shared__ __align__(16) ushort Bs[128 * 64];
    const int tid  = threadIdx.x;
    const int bm   = blockIdx.x * 128;
    const int bn   = blockIdx.y * 128;
    const int w    = tid >> 6, lane = tid & 63;
    const int wm   = (w >> 1) * 64, wn = (w & 1) * 64;
    const int lr   = lane & 15, lk = lane >> 4;
    const int srow = tid >> 3;            // 0..31
    const int sch  = tid & 7;             // 16B chunk

    f32x4 acc[4][4] = {};

    const ushort* Ab = A  + (size_t)(bm + srow) * K + sch * 8;
    const ushort* Bb = Bt + (size_t)(bn + srow) * K + sch * 8;
    ushort* Asd = &As[srow * 64 + sch * 8];
    ushort* Bsd = &Bs[srow * 64 + sch * 8];

    for (int k0 = 0; k0 < K; k0 += 64) {
        #pragma unroll
        for (int c = 0; c < 4; c++)
            gload16(Ab + (size_t)c * 32 * K + k0, Asd + c * 2048);
        #pragma unroll
        for (int c = 0; c < 4; c++)
            gload16(Bb + (size_t)c * 32 * K + k0, Bsd + c * 2048);
        __syncthreads();
        #pragma unroll
        for (int ks = 0; ks < 2; ks++) {
            bf16x8 af[4], bfr[4];
            #pragma unroll
            for (int m = 0; m < 4; m++) {
                int row = wm + m * 16 + lr;
                int byte = (row * 128 + ks * 64 + lk * 16) ^ ((lr & 7) << 4);
                af[m] = *(const bf16x8*)((const char*)As + byte);
            }
            #pragma unroll
            for (int n = 0; n < 4; n++) {
                int row = wn + n * 16 + lr;
                int byte = (row * 128 + ks * 64 + lk * 16) ^ ((lr & 7) << 4);
                bfr[n] = *(const bf16x8*)((const char*)Bs + byte);
            }
            #pragma unroll
            for (int m = 0; m < 4; m++)
                #pragma unroll
                for (int n = 0; n < 4; n++)
                    acc[m][n] = __builtin_amdgcn_mfma_f32_16x16x32_bf16(af[m], bfr[n], acc[m][n], 0, 0, 0);
        }
        __syncthreads();
    }
    // Epilogue. D: col = lane&15, row = (lane>>4)*4 + i
    #pragma unroll
    for (int m = 0; m < 4; m++) {
        int row = bm + wm + m * 16 + lk * 4;
        #pragma unroll
        for (int n = 0; n < 4; n++) {
            int col = bn + wn + n * 16 + lr;
            float bb = bias ? bias[col] : 0.f;
            #pragma unroll
            for (int i = 0; i < 4; i++) {
                float v = acc[m][n][i] + bb;
                if (RELU) v = v > 0.f ? v : 0.f;
                if (OUTBF16) {
                    int cc = SWZOUT ? swzc(row + i, col) : col;
                    Ch[(size_t)(row + i) * N + cc] = f2bf(v);
                } else {
                    Cf[(size_t)(row + i) * N + col] = v;
                }
            }
        }
    }
}

// ---------------------------------------------------------------- GEMM + residual + LayerNorm
// N fixed at 256. 128x256 tile, 8 waves (512 thr) 2x4, per-wave 64x64, acc[4][4]
// (proven register profile). Row stats: 16-lane shfl -> LDS combine over 4 N-waves.
// MODE 0: resid = f32 (src), out = bf16 swizzled (x16)
// MODE 1: resid = bf16 swizzled (x16), out = f32 (d_out)
template<int MODE>
__global__ __launch_bounds__(512) void gemm_ln(
    const ushort* __restrict__ A, const ushort* __restrict__ Bt,
    const float* __restrict__ bias,
    const float* __restrict__ residf, const ushort* __restrict__ residh,
    const float* __restrict__ g, const float* __restrict__ be,
    float* __restrict__ outf, ushort* __restrict__ outh, int K) {
    __shared__ __align__(16) ushort As[128 * 64];   // 16KB
    __shared__ __align__(16) ushort Bs[256 * 64];   // 32KB
    __shared__ float red[4][128][2];                // 4KB
    const int tid  = threadIdx.x;
    const int bm   = blockIdx.x * 128;
    const int w    = tid >> 6, lane = tid & 63;
    const int wm   = (w >> 2) * 64, wn = (w & 3) * 64;
    const int wni  = (w & 3);
    const int lr   = lane & 15, lk = lane >> 4;
    const int srow = tid >> 3, sch = tid & 7;       // srow 0..63

    f32x4 acc[4][4] = {};

    const ushort* Ab = A  + (size_t)(bm + srow) * K + sch * 8;
    const ushort* Bb = Bt + (size_t)srow * K + sch * 8;
    ushort* Asd = &As[srow * 64 + sch * 8];
    ushort* Bsd = &Bs[srow * 64 + sch * 8];

    for (int k0 = 0; k0 < K; k0 += 64) {
        #pragma unroll
        for (int c = 0; c < 2; c++)
            gload16(Ab + (size_t)c * 64 * K + k0, Asd + c * 4096);
        #pragma unroll
        for (int c = 0; c < 4; c++)
            gload16(Bb + (size_t)c * 64 * K + k0, Bsd + c * 4096);
        __syncthreads();
        #pragma unroll
        for (int ks = 0; ks < 2; ks++) {
            bf16x8 af[4], bfr[4];
            #pragma unroll
            for (int m = 0; m < 4; m++) {
                int row = wm + m * 16 + lr;
                int byte = (row * 128 + ks * 64 + lk * 16) ^ ((lr & 7) << 4);
                af[m] = *(const bf16x8*)((const char*)As + byte);
            }
            #pragma unroll
            for (int n = 0; n < 4; n++) {
                int row = wn + n * 16 + lr;
                int byte = (row * 128 + ks * 64 + lk * 16) ^ ((lr & 7) << 4);
                bfr[n] = *(const bf16x8*)((const char*)Bs + byte);
            }
            #pragma unroll
            for (int m = 0; m < 4; m++)
                #pragma unroll
                for (int n = 0; n < 4; n++)
                    acc[m][n] = __builtin_amdgcn_mfma_f32_16x16x32_bf16(af[m], bfr[n], acc[m][n], 0, 0, 0);
        }
        __syncthreads();
    }

    // per-lane column params (cols wn + n*16 + lr)
    float bias_r[4], g_r[4], be_r[4];
    #pragma unroll
    for (int n = 0; n < 4; n++) {
        int col = wn + n * 16 + lr;
        bias_r[n] = bias[col]; g_r[n] = g[col]; be_r[n] = be[col];
    }
    // pass 1: vv = acc + bias + resid (in place), per-wave partial row stats -> LDS
    #pragma unroll
    for (int m = 0; m < 4; m++) {
        #pragma unroll
        for (int i = 0; i < 4; i++) {
            int lrow = wm + m * 16 + lk * 4 + i;
            int row  = bm + lrow;
            float s = 0.f, s2 = 0.f;
            #pragma unroll
            for (int n = 0; n < 4; n++) {
                int col = wn + n * 16 + lr;
                float r;
                if (MODE == 0) r = residf[(size_t)row * 256 + col];
                else           r = bf2f(residh[(size_t)row * 256 + swzc(row, col)]);
                float v = acc[m][n][i] + bias_r[n] + r;
                acc[m][n][i] = v;
                s += v; s2 += v * v;
            }
            #pragma unroll
            for (int msk = 1; msk < 16; msk <<= 1) {
                s += __shfl_xor(s, msk); s2 += __shfl_xor(s2, msk);
            }
            if (lr == 0) { red[wni][lrow][0] = s; red[wni][lrow][1] = s2; }
        }
    }
    __syncthreads();
    // pass 2: combine 4 N-wave partials, normalize, store
    #pragma unroll
    for (int m = 0; m < 4; m++) {
        #pragma unroll
        for (int i = 0; i < 4; i++) {
            int lrow = wm + m * 16 + lk * 4 + i;
            int row  = bm + lrow;
            float s  = red[0][lrow][0] + red[1][lrow][0] + red[2][lrow][0] + red[3][lrow][0];
            float s2 = red[0][lrow][1] + red[1][lrow][1] + red[2][lrow][1] + red[3][lrow][1];
            float mu  = s * (1.f / 256.f);
            float var = s2 * (1.f / 256.f) - mu * mu;
            float rs  = rsqrtf(var + 1e-5f);
            #pragma unroll
            for (int n = 0; n < 4; n++) {
                int col = wn + n * 16 + lr;
                float o = (acc[m][n][i] - mu) * rs * g_r[n] + be_r[n];
                if (MODE == 0) outh[(size_t)row * 256 + swzc(row, col)] = f2bf(o);
                else           outf[(size_t)row * 256 + col] = o;
            }
        }
    }
}

// ---------------------------------------------------------------- deform attn
// 1 wave per (b,query) row; 4 rows per block.
// Phase A: lane = h*8+j computes points {2j,2j+1} of head h -> parity-split LDS records
// Phase B: lane = h*8+j: c8 = j&3 (channel octet), pp = j>>2 (corner parity);
//          32 corners x dwordx4 (8 channels); combine halves via shfl_xor(4).
__global__ __launch_bounds__(256) void deform_attn(
    const ushort* __restrict__ val16,  // [B][LQ][256] bf16 linear
    const ushort* __restrict__ qout,   // [NROW][384] bf16: [0,256)=offs, [256,384)=logits
    const float* __restrict__ rp,      // [NROW][4][2]
    ushort* __restrict__ out16) {      // [NROW][256] bf16 SWIZZLED
    __shared__ __align__(16) unsigned offs_s[4][8][2][36];
    __shared__ __align__(16) float    wgts_s[4][8][2][36];
    const int wid  = threadIdx.x >> 6;
    const int row  = blockIdx.x * 4 + wid;
    const int lane = threadIdx.x & 63;
    const int h    = lane >> 3;
    const int j    = lane & 7;
    const int b    = row / LQ;

    const ushort* qrow = qout + (size_t)row * 384;

    // ---- phase A: softmax (8-lane group reduce) + 2 points per lane
    unsigned lgu = *(const unsigned*)(qrow + 256 + h * 16 + j * 2);
    float lgx = u2f(lgu << 16), lgy = u2f(lgu & 0xffff0000u);
    float m = fmaxf(lgx, lgy);
    m = fmaxf(m, __shfl_xor(m, 1, 8));
    m = fmaxf(m, __shfl_xor(m, 2, 8));
    m = fmaxf(m, __shfl_xor(m, 4, 8));
    float e0 = __expf(lgx - m), e1 = __expf(lgy - m);
    float s = e0 + e1;
    s += __shfl_xor(s, 1, 8);
    s += __shfl_xor(s, 2, 8);
    s += __shfl_xor(s, 4, 8);
    const float inv = 1.f / s;

    const int L  = j >> 1;              // both points of this lane share a level
    const int Wl = 128 >> L;
    const int s0 = (L == 0) ? 0 : (L == 1) ? 16384 : (L == 2) ? 20480 : 21504;
    const float fW = (float)Wl;
    float2 rr = *(const float2*)(rp + (size_t)row * 8 + L * 2);
    uint2 ou  = *(const uint2*)(qrow + h * 32 + j * 4);
    float oxv[2] = { u2f(ou.x << 16), u2f(ou.y << 16) };
    float oyv[2] = { u2f(ou.x & 0xffff0000u), u2f(ou.y & 0xffff0000u) };
    float ev[2]  = { e0, e1 };

    #pragma unroll
    for (int pt = 0; pt < 2; pt++) {
        float aw = ev[pt] * inv;
        int   p  = j * 2 + pt;          // point index 0..15
        float x = rr.x * fW + oxv[pt] - 0.5f;
        float y = rr.y * fW + oyv[pt] - 0.5f;
        float xf = floorf(x), yf = floorf(y);
        float lx = x - xf, ly = y - yf;
        int x0 = (int)xf, y0 = (int)yf;
        int x1 = x0 + 1, y1 = y0 + 1;
        int x0c = min(max(x0, 0), Wl - 1), x1c = min(max(x1, 0), Wl - 1);
        int y0c = min(max(y0, 0), Wl - 1), y1c = min(max(y1, 0), Wl - 1);
        bool vx0 = (unsigned)x0 < (unsigned)Wl, vx1 = (unsigned)x1 < (unsigned)Wl;
        bool vy0 = (unsigned)y0 < (unsigned)Wl, vy1 = (unsigned)y1 < (unsigned)Wl;
        float wx1 = lx, wx0 = 1.f - lx, wy1 = ly, wy0 = 1.f - ly;
        float w00 = (vy0 & vx0) ? aw * wy0 * wx0 : 0.f;
        float w01 = (vy0 & vx1) ? aw * wy0 * wx1 : 0.f;
        float w10 = (vy1 & vx0) ? aw * wy1 * wx0 : 0.f;
        float w11 = (vy1 & vx1) ? aw * wy1 * wx1 : 0.f;
        unsigned hb = (unsigned)h * 64u;
        unsigned o00 = (unsigned)(s0 + y0c * Wl + x0c) * 512u + hb;
        unsigned o01 = (unsigned)(s0 + y0c * Wl + x1c) * 512u + hb;
        unsigned o10 = (unsigned)(s0 + y1c * Wl + x0c) * 512u + hb;
        unsigned o11 = (unsigned)(s0 + y1c * Wl + x1c) * 512u + hb;
        // parity split: corner cc = 4p+k -> [cc&1][cc>>1]; evens {o00(k0),o10(k2)}, odds {o01(k1),o11(k3)}
        *(uint2*)&offs_s[wid][h][0][p * 2] = make_uint2(o00, o10);
        *(uint2*)&offs_s[wid][h][1][p * 2] = make_uint2(o01, o11);
        *(float2*)&wgts_s[wid][h][0][p * 2] = make_float2(w00, w10);
        *(float2*)&wgts_s[wid][h][1][p * 2] = make_float2(w01, w11);
    }
    __syncthreads();

    // ---- phase B: gather 32 corners x 8 channels per lane
    const int c8 = j & 3, pp = j >> 2;
    const int bu = __builtin_amdgcn_readfirstlane(b);  // wave-uniform -> SGPR base
    const char* ubase = (const char*)val16 + (size_t)bu * (LQ * 512);
    const unsigned coff = (unsigned)c8 * 16u;
    const unsigned* po = &offs_s[wid][h][pp][0];
    const float*    pw = &wgts_s[wid][h][pp][0];
    float b0 = 0.f, b1v = 0.f, b2v = 0.f, b3 = 0.f, b4 = 0.f, b5 = 0.f, b6 = 0.f, b7 = 0.f;
    #pragma unroll
    for (int t4 = 0; t4 < 8; t4++) {
        uint4  oo = *(const uint4*)(po + t4 * 4);
        float4 ww = *(const float4*)(pw + t4 * 4);
        uint4 u0 = *(const uint4*)(ubase + (oo.x + coff));
        uint4 u1 = *(const uint4*)(ubase + (oo.y + coff));
        uint4 u2 = *(const uint4*)(ubase + (oo.z + coff));
        uint4 u3 = *(const uint4*)(ubase + (oo.w + coff));
        b0 += ww.x * u2f(u0.x << 16); b1v += ww.x * u2f(u0.x);
        b2v += ww.x * u2f(u0.y << 16); b3 += ww.x * u2f(u0.y);
        b4 += ww.x * u2f(u0.z << 16); b5 += ww.x * u2f(u0.z);
        b6 += ww.x * u2f(u0.w << 16); b7 += ww.x * u2f(u0.w);
        b0 += ww.y * u2f(u1.x << 16); b1v += ww.y * u2f(u1.x);
        b2v += ww.y * u2f(u1.y << 16); b3 += ww.y * u2f(u1.y);
        b4 += ww.y * u2f(u1.z << 16); b5 += ww.y * u2f(u1.z);
        b6 += ww.y * u2f(u1.w << 16); b7 += ww.y * u2f(u1.w);
        b0 += ww.z * u2f(u2.x << 16); b1v += ww.z * u2f(u2.x);
        b2v += ww.z * u2f(u2.y << 16); b3 += ww.z * u2f(u2.y);
        b4 += ww.z * u2f(u2.z << 16); b5 += ww.z * u2f(u2.z);
        b6 += ww.z * u2f(u2.w << 16); b7 += ww.z * u2f(u2.w);
        b0 += ww.w * u2f(u3.x << 16); b1v += ww.w * u2f(u3.x);
        b2v += ww.w * u2f(u3.y << 16); b3 += ww.w * u2f(u3.y);
        b4 += ww.w * u2f(u3.z << 16); b5 += ww.w * u2f(u3.z);
        b6 += ww.w * u2f(u3.w << 16); b7 += ww.w * u2f(u3.w);
    }
    // combine parity halves (lane j <-> j^4, same head, same c8)
    b0 += __shfl_xor(b0, 4); b1v += __shfl_xor(b1v, 4);
    b2v += __shfl_xor(b2v, 4); b3 += __shfl_xor(b3, 4);
    b4 += __shfl_xor(b4, 4); b5 += __shfl_xor(b5, 4);
    b6 += __shfl_xor(b6, 4); b7 += __shfl_xor(b7, 4);
    if (pp == 0) {
        uint4 o;
        o.x = (unsigned)f2bf(b0) | ((unsigned)f2bf(b1v) << 16);
        o.y = (unsigned)f2bf(b2v) | ((unsigned)f2bf(b3) << 16);
        o.z = (unsigned)f2bf(b4) | ((unsigned)f2bf(b5) << 16);
        o.w = (unsigned)f2bf(b6) | ((unsigned)f2bf(b7) << 16);
        int col = h * 32 + c8 * 8;     // chunk-aligned: swzc keeps 16B contiguous
        *(uint4*)(out16 + (size_t)row * 256 + swzc(row, col)) = o;
    }
}

// ---------------------------------------------------------------- launch
extern "C" void kernel_launch(void* const* d_in, const int* in_sizes, int n_in,
                              void* d_out, int out_size, void* d_ws, size_t ws_size,
                              hipStream_t stream) {
    const float* src  = (const float*)d_in[0];
    const float* pos  = (const float*)d_in[1];
    const float* rp   = (const float*)d_in[2];
    const float* Wv   = (const float*)d_in[5];  const float* bv   = (const float*)d_in[6];
    const float* Woff = (const float*)d_in[7];  const float* boff = (const float*)d_in[8];
    const float* Wa   = (const float*)d_in[9];  const float* ba   = (const float*)d_in[10];
    const float* Wo   = (const float*)d_in[11]; const float* bo   = (const float*)d_in[12];
    const float* W1   = (const float*)d_in[13]; const float* b1   = (const float*)d_in[14];
    const float* W2   = (const float*)d_in[15]; const float* b2   = (const float*)d_in[16];
    const float* g1   = (const float*)d_in[17]; const float* be1  = (const float*)d_in[18];
    const float* g2w  = (const float*)d_in[19]; const float* be2  = (const float*)d_in[20];

    char* ws = (char*)d_ws;
    ushort* s16    = (ushort*)(ws + 0);            // 22,282,240 (swz)
    ushort* q16    = (ushort*)(ws + 22282240);     // 22,282,240 (swz)
    ushort* val16  = (ushort*)(ws + 44564480);     // 22,282,240 (linear)
    ushort* qout16 = (ushort*)(ws + 66846720);     // 33,423,360 (linear, [NROW][384])
    ushort* def16  = (ushort*)(ws + 100270080);    // 22,282,240 (swz)
    ushort* x16    = (ushort*)(ws + 144834560);    // 22,282,240 (swz)
    ushort* wts    = (ushort*)(ws + 167116800);    // ~1.5 MB
    ushort* hid16  = (ushort*)(ws + 44564480);     // reuse val16+qout16+def16 (89,128,960; swz)

    ushort* WvT = wts;
    ushort* WqT = WvT + 65536;      // [384][256] (Woff|Wa)
    ushort* WoT = WqT + 98304;
    ushort* W1T = WoT + 65536;
    ushort* W2T = W1T + 262144;
    float*  bq  = (float*)(W2T + 262144);  // [384] = boff|ba

    wtrans_all<<<2946, 256, 0, stream>>>(Wv, Woff, Wa, Wo, W1, W2, boff, ba,
                                         WvT, WqT, WoT, W1T, W2T, bq);

    addpos_cast<<<2048, 256, 0, stream>>>(src, pos, s16, q16);

    dim3 gv2(NROW / 128, 2), gq3(NROW / 128, 3), gf8(NROW / 128, 8);
    gemm_bf16<0,1,0><<<gv2, 256, 0, stream>>>(s16, WvT, bv, nullptr, val16,  256, 256);
    gemm_bf16<0,1,0><<<gq3, 256, 0, stream>>>(q16, WqT, bq, nullptr, qout16, 256, 384);

    deform_attn<<<NROW / 4, 256, 0, stream>>>(val16, qout16, rp, def16);

    // Wo GEMM + residual(src) + LN1 -> x16 (swz bf16)
    gemm_ln<0><<<dim3(NROW / 128), 512, 0, stream>>>(
        def16, WoT, bo, src, nullptr, g1, be1, nullptr, x16, 256);

    gemm_bf16<1,1,1><<<gf8, 256, 0, stream>>>(x16, W1T, b1, nullptr, hid16, 256, 1024);

    // W2 GEMM + residual(x16) + LN2 -> d_out (f32)
    gemm_ln<1><<<dim3(NROW / 128), 512, 0, stream>>>(
        hid16, W2T, b2, nullptr, x16, g2w, be2, (float*)d_out, nullptr, 1024);
}